// Round 8
// baseline (845.039 us; speedup 1.0000x reference)
//
#include <hip/hip_runtime.h>
#include <hip/hip_bf16.h>

#define NN 100000
#define NE 600000

__device__ __forceinline__ float dot4(float4 a, float4 b){
  return a.x*b.x + a.y*b.y + a.z*b.z + a.w*b.w;
}
__device__ __forceinline__ void fma4(float4& a, float s, float4 w){
  a.x += s*w.x; a.y += s*w.y; a.z += s*w.z; a.w += s*w.w;
}

// ---------------- CSR build (dst-grouped) ----------------
__global__ void count_edges(const int* __restrict__ dst, int* __restrict__ cnt){
  int e = blockIdx.x*256 + threadIdx.x;
  if (e < NE){
    unsigned d = (unsigned)dst[e];
    if (d < NN) atomicAdd(&cnt[d], 1);
  }
}

__global__ void scan1(const int* __restrict__ cnt, int* __restrict__ offs, int* __restrict__ bsum){
  __shared__ int sh[256];
  const int tid = threadIdx.x;
  const int base = blockIdx.x*2048 + tid*8;
  int pre[8]; int s = 0;
  #pragma unroll
  for (int j=0;j<8;j++){
    int idx = base + j;
    int v = (idx < NN) ? cnt[idx] : 0;
    pre[j] = s; s += v;
  }
  sh[tid] = s;
  __syncthreads();
  for (int d=1; d<256; d<<=1){
    int t = (tid >= d) ? sh[tid-d] : 0;
    __syncthreads();
    sh[tid] += t;
    __syncthreads();
  }
  int off = (tid > 0) ? sh[tid-1] : 0;
  #pragma unroll
  for (int j=0;j<8;j++){
    int idx = base + j;
    if (idx < NN) offs[idx] = off + pre[j];
  }
  if (tid == 255) bsum[blockIdx.x] = sh[255];
}

__global__ void scan2(int* __restrict__ bsum){
  if (threadIdx.x == 0){
    int s = 0;
    for (int i=0;i<49;i++){ int t = bsum[i]; bsum[i] = s; s += t; }
  }
}

__global__ void scan3(int* __restrict__ offs, const int* __restrict__ bsum, int* __restrict__ cursor){
  int i = blockIdx.x*256 + threadIdx.x;
  if (i < NN){
    int v = offs[i] + bsum[i>>11];
    offs[i] = v; cursor[i] = v;
  }
  if (i == 0) offs[NN] = NE;
}

__global__ void fill_csr(const int* __restrict__ src, const int* __restrict__ dst,
                         int* __restrict__ cursor, int* __restrict__ csrsrc){
  int e = blockIdx.x*256 + threadIdx.x;
  if (e < NE){
    unsigned d = (unsigned)dst[e];
    unsigned s = (unsigned)src[e];
    if (d < NN && s < NN){
      int p = atomicAdd(&cursor[d], 1);
      csrsrc[p] = (int)s;
    }
  }
}

// ---------------- input MLP: h = relu(LN(x@w_in+b_in)) ----------------
__global__ __launch_bounds__(256) void input_mlp(const float* __restrict__ x,
    const float* __restrict__ win, const float* __restrict__ b,
    const float* __restrict__ lnw, const float* __restrict__ lnb,
    float* __restrict__ h)
{
  __shared__ float wsh[6*128];
  __shared__ float p2[4][2];
  const int tid = threadIdx.x;
  for (int i=tid;i<768;i+=256) wsh[i] = win[i];
  __syncthreads();
  const int nl = tid>>7, c = tid&127;
  const int n = blockIdx.x*2 + nl;
  float s = b[c];
  #pragma unroll
  for (int k=0;k<6;k++) s += x[n*6+k]*wsh[k*128+c];
  float sum = s, sq = s*s;
  #pragma unroll
  for (int o=32;o>=1;o>>=1){ sum += __shfl_xor(sum,o); sq += __shfl_xor(sq,o); }
  const int wv = tid>>6;
  if ((tid&63)==0){ p2[wv][0]=sum; p2[wv][1]=sq; }
  __syncthreads();
  float ts = p2[nl*2][0]+p2[nl*2+1][0];
  float tq = p2[nl*2][1]+p2[nl*2+1][1];
  float mean = ts*(1.f/128.f);
  float var  = tq*(1.f/128.f) - mean*mean;
  float y = (s-mean)*rsqrtf(var+1e-5f)*lnw[c]+lnb[c];
  h[(size_t)n*128+c] = fmaxf(y, 0.f);
}

// ---------------- tiled fp32 GEMM: Y = act(LN?(X@W + b)), X is Nx128 ----------------
// K-chunked W staging (KC=32 rows, 16 KB for C=128) + register double-buffer
// prefetch of the next chunk. LDS = 32 KB (C=128) / 24 KB (C=64) -> 5-6
// blocks/CU instead of 2 (was 80 KB with full-W staging).
template<int C, bool HAS_BIAS, bool DO_LN, bool DO_RELU, bool GAT>
__global__ __launch_bounds__(256) void gemm128(const float* __restrict__ X,
    const float* __restrict__ W, const float* __restrict__ bias,
    const float* __restrict__ lnw, const float* __restrict__ lnb,
    const float* __restrict__ asrc, const float* __restrict__ adst,
    float* __restrict__ Y, float* __restrict__ als, float* __restrict__ ald)
{
  constexpr int TPC = C/4;        // threads covering one row's channels
  constexpr int NG  = 256/TPC;    // row groups per pass
  constexpr int NPB = 32;         // nodes per block
  constexpr int RPT = NPB/NG;     // rows per thread
  constexpr int KC  = 32;         // k-chunk rows staged at a time
  constexpr int CF4 = KC*C/4;     // float4 per chunk
  constexpr int NW  = CF4/256;    // float4 per thread per chunk (4 for C=128)
  __shared__ float Wsh[KC*C];
  __shared__ float Xsh[NPB*128];
  const int tid = threadIdx.x;
  const float4* W4 = (const float4*)W;
  float4 wreg[NW];
  #pragma unroll
  for (int j=0;j<NW;j++) wreg[j] = W4[tid + j*256];      // prefetch chunk 0
  {
    const float4* X4 = (const float4*)(X + (size_t)blockIdx.x*NPB*128);
    float4* XS = (float4*)Xsh;
    for (int i=tid; i<NPB*128/4; i+=256) XS[i] = X4[i];
  }
  const int tc = tid % TPC, tg = tid / TPC;
  float4 acc[RPT];
  float4 bv = make_float4(0.f,0.f,0.f,0.f);
  if constexpr (HAS_BIAS) bv = ((const float4*)bias)[tc];
  #pragma unroll
  for (int r=0;r<RPT;r++) acc[r] = bv;

  for (int kc=0; kc<128; kc+=KC){
    __syncthreads();                       // prev chunk's reads done (covers Xsh on iter 0)
    {
      float4* S4 = (float4*)Wsh;
      #pragma unroll
      for (int j=0;j<NW;j++) S4[tid + j*256] = wreg[j];
    }
    if (kc + KC < 128){
      const int base = (kc+KC)*C/4;
      #pragma unroll
      for (int j=0;j<NW;j++) wreg[j] = W4[base + tid + j*256];  // prefetch next
    }
    __syncthreads();
    #pragma unroll 4
    for (int k=0;k<KC;k+=4){
      float4 w0 = *(const float4*)&Wsh[(k+0)*C + tc*4];
      float4 w1 = *(const float4*)&Wsh[(k+1)*C + tc*4];
      float4 w2 = *(const float4*)&Wsh[(k+2)*C + tc*4];
      float4 w3 = *(const float4*)&Wsh[(k+3)*C + tc*4];
      #pragma unroll
      for (int r=0;r<RPT;r++){
        float4 xv = *(const float4*)&Xsh[(tg + r*NG)*128 + kc + k];
        fma4(acc[r], xv.x, w0); fma4(acc[r], xv.y, w1);
        fma4(acc[r], xv.z, w2); fma4(acc[r], xv.w, w3);
      }
    }
  }

  const int n0 = blockIdx.x*NPB;
  if constexpr (GAT){
    float4 av = ((const float4*)asrc)[tc];
    float4 dv = ((const float4*)adst)[tc];
    #pragma unroll
    for (int r=0;r<RPT;r++){
      const int n = n0 + tg + r*NG;
      ((float4*)&Y[(size_t)n*C])[tc] = acc[r];
      float ps = dot4(acc[r], av), pd = dot4(acc[r], dv);
      ps += __shfl_xor(ps,1); ps += __shfl_xor(ps,2);
      pd += __shfl_xor(pd,1); pd += __shfl_xor(pd,2);
      if ((tc&3)==0){
        als[n*8 + (tc>>2)] = ps;
        ald[n*8 + (tc>>2)] = pd;
      }
    }
  } else {
    #pragma unroll
    for (int r=0;r<RPT;r++){
      float4 v = acc[r];
      if constexpr (DO_LN){
        float s = v.x+v.y+v.z+v.w;
        float q = dot4(v,v);
        #pragma unroll
        for (int o=1;o<TPC;o<<=1){ s += __shfl_xor(s,o); q += __shfl_xor(q,o); }
        float mean = s*(1.0f/C);
        float var  = q*(1.0f/C) - mean*mean;
        float rr = rsqrtf(var + 1e-5f);
        float4 lw = ((const float4*)lnw)[tc];
        float4 lb = ((const float4*)lnb)[tc];
        v.x = (v.x-mean)*rr*lw.x + lb.x;
        v.y = (v.y-mean)*rr*lw.y + lb.y;
        v.z = (v.z-mean)*rr*lw.z + lb.z;
        v.w = (v.w-mean)*rr*lw.w + lb.w;
      }
      if constexpr (DO_RELU){
        v.x=fmaxf(v.x,0.f); v.y=fmaxf(v.y,0.f); v.z=fmaxf(v.z,0.f); v.w=fmaxf(v.w,0.f);
      }
      const int n = n0 + tg + r*NG;
      ((float4*)&Y[(size_t)n*C])[tc] = v;
    }
  }
}

// ---------------- per-node softmax + aggregate + LN + residual ----------------
// One wave per node, lane = channel pair (c, c+64). No max-subtraction:
// logits are O(1) (0.05-scale weights), so exp() is safe in fp32 and softmax
// is shift-invariant. Each lane redundantly computes its head's p=exp(logit)
// (broadcast loads) and accumulates acc & denom privately -> zero cross-lane
// ops in the edge loop, no LDS, no barriers. Edge loop unrolled 4/2/1 for ILP.
__global__ __launch_bounds__(256) void gat_aggregate(
    const float* __restrict__ xw, const float* __restrict__ als, const float* __restrict__ ald,
    const int* __restrict__ offs, const int* __restrict__ csrsrc,
    const float* __restrict__ bg, const float* __restrict__ lnw, const float* __restrict__ lnb,
    float* __restrict__ h)
{
  const int wv = threadIdx.x >> 6, lane = threadIdx.x & 63;
  const int n = blockIdx.x*4 + wv;
  const int h0 = lane >> 4;                 // head of channel c=lane; c+64 -> h0+4
  const float ad0 = ald[n*8 + h0];
  const float ad1 = ald[n*8 + h0 + 4];

  // self-loop
  float t0 = als[n*8 + h0] + ad0;     t0 = t0 > 0.f ? t0 : 0.2f*t0;
  float t1 = als[n*8 + h0 + 4] + ad1; t1 = t1 > 0.f ? t1 : 0.2f*t1;
  float p0 = __expf(t0), p1 = __expf(t1);
  float s0 = p0, s1 = p1;
  float acc0 = p0 * xw[(size_t)n*128 + lane];
  float acc1 = p1 * xw[(size_t)n*128 + 64 + lane];

  const int start = offs[n], end = offs[n+1];
  int e = start;
  for (; e+4 <= end; e += 4){
    int s4[4]; float a0[4], a1[4], x0[4], x1[4];
    #pragma unroll
    for (int j=0;j<4;j++) s4[j] = csrsrc[e+j];
    #pragma unroll
    for (int j=0;j<4;j++){
      a0[j] = als[s4[j]*8 + h0];
      a1[j] = als[s4[j]*8 + h0 + 4];
      x0[j] = xw[(size_t)s4[j]*128 + lane];
      x1[j] = xw[(size_t)s4[j]*128 + 64 + lane];
    }
    #pragma unroll
    for (int j=0;j<4;j++){
      float u0 = a0[j] + ad0; u0 = u0 > 0.f ? u0 : 0.2f*u0;
      float q0 = __expf(u0);
      s0 += q0; acc0 = fmaf(q0, x0[j], acc0);
      float u1 = a1[j] + ad1; u1 = u1 > 0.f ? u1 : 0.2f*u1;
      float q1 = __expf(u1);
      s1 += q1; acc1 = fmaf(q1, x1[j], acc1);
    }
  }
  if (e+2 <= end){
    int sA = csrsrc[e], sB = csrsrc[e+1];
    float aA0 = als[sA*8+h0], aA1 = als[sA*8+h0+4];
    float aB0 = als[sB*8+h0], aB1 = als[sB*8+h0+4];
    float xA0 = xw[(size_t)sA*128+lane], xA1 = xw[(size_t)sA*128+64+lane];
    float xB0 = xw[(size_t)sB*128+lane], xB1 = xw[(size_t)sB*128+64+lane];
    float u;
    u = aA0+ad0; u = u>0.f?u:0.2f*u; float qA0 = __expf(u);
    u = aA1+ad1; u = u>0.f?u:0.2f*u; float qA1 = __expf(u);
    u = aB0+ad0; u = u>0.f?u:0.2f*u; float qB0 = __expf(u);
    u = aB1+ad1; u = u>0.f?u:0.2f*u; float qB1 = __expf(u);
    s0 += qA0+qB0; s1 += qA1+qB1;
    acc0 = fmaf(qA0, xA0, fmaf(qB0, xB0, acc0));
    acc1 = fmaf(qA1, xA1, fmaf(qB1, xB1, acc1));
    e += 2;
  }
  if (e < end){
    int sA = csrsrc[e];
    float aA0 = als[sA*8+h0], aA1 = als[sA*8+h0+4];
    float xA0 = xw[(size_t)sA*128+lane], xA1 = xw[(size_t)sA*128+64+lane];
    float u;
    u = aA0+ad0; u = u>0.f?u:0.2f*u; float qA0 = __expf(u);
    u = aA1+ad1; u = u>0.f?u:0.2f*u; float qA1 = __expf(u);
    s0 += qA0; s1 += qA1;
    acc0 = fmaf(qA0, xA0, acc0);
    acc1 = fmaf(qA1, xA1, acc1);
  }

  float val0 = acc0/s0 + bg[lane];
  float val1 = acc1/s1 + bg[64+lane];
  // LayerNorm across 128 channels = butterfly over this wave (2 ch/lane)
  float sum = val0+val1, sq = val0*val0 + val1*val1;
  #pragma unroll
  for (int off=32; off>=1; off>>=1){ sum += __shfl_xor(sum,off); sq += __shfl_xor(sq,off); }
  float mean = sum*(1.f/128.f);
  float var  = sq*(1.f/128.f) - mean*mean;
  float rr = rsqrtf(var + 1e-5f);
  float y0 = (val0-mean)*rr*lnw[lane]    + lnb[lane];
  float y1 = (val1-mean)*rr*lnw[64+lane] + lnb[64+lane];
  h[(size_t)n*128+lane]    += fmaxf(y0, 0.f);
  h[(size_t)n*128+64+lane] += fmaxf(y1, 0.f);
}

// ---------------- final projection: out = o2@w3 + b3 ----------------
__global__ __launch_bounds__(256) void out_proj(const float* __restrict__ o2,
    const float* __restrict__ w3, const float* __restrict__ b3, float* __restrict__ out)
{
  __shared__ float wsh[256];
  const int tid = threadIdx.x;
  wsh[tid] = w3[tid];
  __syncthreads();
  const int g = blockIdx.x*64 + (tid>>2);
  if (g >= NN) return;
  const int oc = tid&3;
  float s = b3[oc];
  const float* row = &o2[(size_t)g*64];
  #pragma unroll 8
  for (int k=0;k<64;k++) s += row[k]*wsh[k*4+oc];
  out[(size_t)g*4+oc] = s;
}

extern "C" void kernel_launch(void* const* d_in, const int* in_sizes, int n_in,
                              void* d_out, int out_size, void* d_ws, size_t ws_size,
                              hipStream_t stream)
{
  const float* x       = (const float*)d_in[0];
  const int*   ei      = (const int*)d_in[1];
  const float* w_in    = (const float*)d_in[2];
  const float* b_in    = (const float*)d_in[3];
  const float* ln_in_w = (const float*)d_in[4];
  const float* ln_in_b = (const float*)d_in[5];
  const float* Wg      = (const float*)d_in[6];
  const float* a_src   = (const float*)d_in[7];
  const float* a_dst   = (const float*)d_in[8];
  const float* bg      = (const float*)d_in[9];
  const float* lnw     = (const float*)d_in[10];
  const float* lnb     = (const float*)d_in[11];
  const float* w1      = (const float*)d_in[12];
  const float* b1      = (const float*)d_in[13];
  const float* lnow    = (const float*)d_in[14];
  const float* lnob    = (const float*)d_in[15];
  const float* w2      = (const float*)d_in[16];
  const float* b2      = (const float*)d_in[17];
  const float* w3      = (const float*)d_in[18];
  const float* b3      = (const float*)d_in[19];
  float* out = (float*)d_out;

  char* p = (char*)d_ws;
  auto carve = [&](size_t bytes)->void*{
    void* r = (void*)p; p += (bytes + 255) & ~(size_t)255; return r;
  };
  float* h    = (float*)carve((size_t)NN*128*4);
  float* xw   = (float*)carve((size_t)NN*128*4);
  float* als  = (float*)carve((size_t)NN*8*4);
  float* ald  = (float*)carve((size_t)NN*8*4);
  int* offs   = (int*)carve((size_t)(NN+1)*4);
  int* cursor = (int*)carve((size_t)NN*4);
  int* cnt    = (int*)carve((size_t)NN*4);
  int* csrsrc = (int*)carve((size_t)NE*4);
  int* bsum   = (int*)carve(64*4);
  float* o2   = h;

  const int* esrc = ei;
  const int* edst = ei + NE;

  hipMemsetAsync(cnt, 0, (size_t)NN*4, stream);
  count_edges<<<(NE+255)/256, 256, 0, stream>>>(edst, cnt);
  scan1<<<49, 256, 0, stream>>>(cnt, offs, bsum);
  scan2<<<1, 64, 0, stream>>>(bsum);
  scan3<<<(NN+255)/256, 256, 0, stream>>>(offs, bsum, cursor);
  fill_csr<<<(NE+255)/256, 256, 0, stream>>>(esrc, edst, cursor, csrsrc);

  input_mlp<<<NN/2, 256, 0, stream>>>(x, w_in, b_in, ln_in_w, ln_in_b, h);

  for (int i=0;i<4;i++){
    gemm128<128,false,false,false,true><<<NN/32, 256, 0, stream>>>(
        h, Wg + (size_t)i*128*128, nullptr, nullptr, nullptr,
        a_src + i*128, a_dst + i*128, xw, als, ald);
    gat_aggregate<<<NN/4, 256, 0, stream>>>(xw, als, ald, offs, csrsrc,
        bg + i*128, lnw + i*128, lnb + i*128, h);
  }

  gemm128<128,true,true,true,false><<<NN/32, 256, 0, stream>>>(
      h, w1, b1, lnow, lnob, nullptr, nullptr, xw, nullptr, nullptr);
  gemm128<64,true,false,true,false><<<NN/32, 256, 0, stream>>>(
      xw, w2, b2, nullptr, nullptr, nullptr, nullptr, o2, nullptr, nullptr);
  out_proj<<<(NN+63)/64, 256, 0, stream>>>(o2, w3, b3, out);
}

// Round 9
// 779.950 us; speedup vs baseline: 1.0835x; 1.0835x over previous
//
#include <hip/hip_runtime.h>
#include <hip/hip_bf16.h>

#define NN 100000
#define NE 600000

__device__ __forceinline__ float dot4(float4 a, float4 b){
  return a.x*b.x + a.y*b.y + a.z*b.z + a.w*b.w;
}
__device__ __forceinline__ void fma4(float4& a, float s, float4 w){
  a.x += s*w.x; a.y += s*w.y; a.z += s*w.z; a.w += s*w.w;
}

// ---------------- CSR build (dst-grouped) ----------------
__global__ void count_edges(const int* __restrict__ dst, int* __restrict__ cnt){
  int e = blockIdx.x*256 + threadIdx.x;
  if (e < NE){
    unsigned d = (unsigned)dst[e];
    if (d < NN) atomicAdd(&cnt[d], 1);
  }
}

__global__ void scan1(const int* __restrict__ cnt, int* __restrict__ offs, int* __restrict__ bsum){
  __shared__ int sh[256];
  const int tid = threadIdx.x;
  const int base = blockIdx.x*2048 + tid*8;
  int pre[8]; int s = 0;
  #pragma unroll
  for (int j=0;j<8;j++){
    int idx = base + j;
    int v = (idx < NN) ? cnt[idx] : 0;
    pre[j] = s; s += v;
  }
  sh[tid] = s;
  __syncthreads();
  for (int d=1; d<256; d<<=1){
    int t = (tid >= d) ? sh[tid-d] : 0;
    __syncthreads();
    sh[tid] += t;
    __syncthreads();
  }
  int off = (tid > 0) ? sh[tid-1] : 0;
  #pragma unroll
  for (int j=0;j<8;j++){
    int idx = base + j;
    if (idx < NN) offs[idx] = off + pre[j];
  }
  if (tid == 255) bsum[blockIdx.x] = sh[255];
}

__global__ void scan2(int* __restrict__ bsum){
  if (threadIdx.x == 0){
    int s = 0;
    for (int i=0;i<49;i++){ int t = bsum[i]; bsum[i] = s; s += t; }
  }
}

__global__ void scan3(int* __restrict__ offs, const int* __restrict__ bsum, int* __restrict__ cursor){
  int i = blockIdx.x*256 + threadIdx.x;
  if (i < NN){
    int v = offs[i] + bsum[i>>11];
    offs[i] = v; cursor[i] = v;
  }
  if (i == 0) offs[NN] = NE;
}

__global__ void fill_csr(const int* __restrict__ src, const int* __restrict__ dst,
                         int* __restrict__ cursor, int* __restrict__ csrsrc){
  int e = blockIdx.x*256 + threadIdx.x;
  if (e < NE){
    unsigned d = (unsigned)dst[e];
    unsigned s = (unsigned)src[e];
    if (d < NN && s < NN){
      int p = atomicAdd(&cursor[d], 1);
      csrsrc[p] = (int)s;
    }
  }
}

// ---------------- input MLP: h = relu(LN(x@w_in+b_in)) ----------------
__global__ __launch_bounds__(256) void input_mlp(const float* __restrict__ x,
    const float* __restrict__ win, const float* __restrict__ b,
    const float* __restrict__ lnw, const float* __restrict__ lnb,
    float* __restrict__ h)
{
  __shared__ float wsh[6*128];
  __shared__ float p2[4][2];
  const int tid = threadIdx.x;
  for (int i=tid;i<768;i+=256) wsh[i] = win[i];
  __syncthreads();
  const int nl = tid>>7, c = tid&127;
  const int n = blockIdx.x*2 + nl;
  float s = b[c];
  #pragma unroll
  for (int k=0;k<6;k++) s += x[n*6+k]*wsh[k*128+c];
  float sum = s, sq = s*s;
  #pragma unroll
  for (int o=32;o>=1;o>>=1){ sum += __shfl_xor(sum,o); sq += __shfl_xor(sq,o); }
  const int wv = tid>>6;
  if ((tid&63)==0){ p2[wv][0]=sum; p2[wv][1]=sq; }
  __syncthreads();
  float ts = p2[nl*2][0]+p2[nl*2+1][0];
  float tq = p2[nl*2][1]+p2[nl*2+1][1];
  float mean = ts*(1.f/128.f);
  float var  = tq*(1.f/128.f) - mean*mean;
  float y = (s-mean)*rsqrtf(var+1e-5f)*lnw[c]+lnb[c];
  h[(size_t)n*128+c] = fmaxf(y, 0.f);
}

// ---------------- tiled fp32 GEMM: Y = act(LN?(X@W + b)), X is Nx128 ----------------
// X (32 nodes, 16 KB) staged in LDS; W streamed directly from global (L2-resident:
// all blocks read the same 64 KB). Wave W-loads touch 512 contiguous bytes
// (coalesced L2 hits); Xsh reads are same-address broadcasts (conflict-free).
// No W staging -> no cross-barrier register liveness -> no spills; LDS=16 KB.
template<int C, bool HAS_BIAS, bool DO_LN, bool DO_RELU, bool GAT>
__global__ __launch_bounds__(256) void gemm128(const float* __restrict__ X,
    const float* __restrict__ W, const float* __restrict__ bias,
    const float* __restrict__ lnw, const float* __restrict__ lnb,
    const float* __restrict__ asrc, const float* __restrict__ adst,
    float* __restrict__ Y, float* __restrict__ als, float* __restrict__ ald)
{
  constexpr int TPC = C/4;        // threads covering one row's channels
  constexpr int NG  = 256/TPC;    // row groups per pass
  constexpr int NPB = 32;         // nodes per block
  constexpr int RPT = NPB/NG;     // rows per thread
  __shared__ float Xsh[NPB*128];
  const int tid = threadIdx.x;
  {
    const float4* X4 = (const float4*)(X + (size_t)blockIdx.x*NPB*128);
    float4* XS = (float4*)Xsh;
    for (int i=tid; i<NPB*128/4; i+=256) XS[i] = X4[i];
  }
  __syncthreads();
  const int tc = tid % TPC, tg = tid / TPC;
  const float4* Wc = (const float4*)W + tc;   // column slice of W
  float4 acc[RPT];
  float4 bv = make_float4(0.f,0.f,0.f,0.f);
  if constexpr (HAS_BIAS) bv = ((const float4*)bias)[tc];
  #pragma unroll
  for (int r=0;r<RPT;r++) acc[r] = bv;
  #pragma unroll 2
  for (int k=0;k<128;k+=4){
    float4 w0 = Wc[(k+0)*TPC];
    float4 w1 = Wc[(k+1)*TPC];
    float4 w2 = Wc[(k+2)*TPC];
    float4 w3 = Wc[(k+3)*TPC];
    #pragma unroll
    for (int r=0;r<RPT;r++){
      float4 xv = *(const float4*)&Xsh[(tg + r*NG)*128 + k];
      fma4(acc[r], xv.x, w0); fma4(acc[r], xv.y, w1);
      fma4(acc[r], xv.z, w2); fma4(acc[r], xv.w, w3);
    }
  }
  const int n0 = blockIdx.x*NPB;
  if constexpr (GAT){
    float4 av = ((const float4*)asrc)[tc];
    float4 dv = ((const float4*)adst)[tc];
    #pragma unroll
    for (int r=0;r<RPT;r++){
      const int n = n0 + tg + r*NG;
      ((float4*)&Y[(size_t)n*C])[tc] = acc[r];
      float ps = dot4(acc[r], av), pd = dot4(acc[r], dv);
      ps += __shfl_xor(ps,1); ps += __shfl_xor(ps,2);
      pd += __shfl_xor(pd,1); pd += __shfl_xor(pd,2);
      if ((tc&3)==0){
        als[n*8 + (tc>>2)] = ps;
        ald[n*8 + (tc>>2)] = pd;
      }
    }
  } else {
    #pragma unroll
    for (int r=0;r<RPT;r++){
      float4 v = acc[r];
      if constexpr (DO_LN){
        float s = v.x+v.y+v.z+v.w;
        float q = dot4(v,v);
        #pragma unroll
        for (int o=1;o<TPC;o<<=1){ s += __shfl_xor(s,o); q += __shfl_xor(q,o); }
        float mean = s*(1.0f/C);
        float var  = q*(1.0f/C) - mean*mean;
        float rr = rsqrtf(var + 1e-5f);
        float4 lw = ((const float4*)lnw)[tc];
        float4 lb = ((const float4*)lnb)[tc];
        v.x = (v.x-mean)*rr*lw.x + lb.x;
        v.y = (v.y-mean)*rr*lw.y + lb.y;
        v.z = (v.z-mean)*rr*lw.z + lb.z;
        v.w = (v.w-mean)*rr*lw.w + lb.w;
      }
      if constexpr (DO_RELU){
        v.x=fmaxf(v.x,0.f); v.y=fmaxf(v.y,0.f); v.z=fmaxf(v.z,0.f); v.w=fmaxf(v.w,0.f);
      }
      const int n = n0 + tg + r*NG;
      ((float4*)&Y[(size_t)n*C])[tc] = v;
    }
  }
}

// ---------------- per-node softmax + aggregate + LN + residual ----------------
// One wave per node, lane = channel pair (c, c+64). No max-subtraction:
// logits are O(1) (0.05-scale weights), so exp() is safe in fp32 and softmax
// is shift-invariant. Private per-lane accumulation, no LDS, no barriers.
__global__ __launch_bounds__(256) void gat_aggregate(
    const float* __restrict__ xw, const float* __restrict__ als, const float* __restrict__ ald,
    const int* __restrict__ offs, const int* __restrict__ csrsrc,
    const float* __restrict__ bg, const float* __restrict__ lnw, const float* __restrict__ lnb,
    float* __restrict__ h)
{
  const int wv = threadIdx.x >> 6, lane = threadIdx.x & 63;
  const int n = blockIdx.x*4 + wv;
  const int h0 = lane >> 4;                 // head of channel c=lane; c+64 -> h0+4
  const float ad0 = ald[n*8 + h0];
  const float ad1 = ald[n*8 + h0 + 4];

  // self-loop
  float t0 = als[n*8 + h0] + ad0;     t0 = t0 > 0.f ? t0 : 0.2f*t0;
  float t1 = als[n*8 + h0 + 4] + ad1; t1 = t1 > 0.f ? t1 : 0.2f*t1;
  float p0 = __expf(t0), p1 = __expf(t1);
  float s0 = p0, s1 = p1;
  float acc0 = p0 * xw[(size_t)n*128 + lane];
  float acc1 = p1 * xw[(size_t)n*128 + 64 + lane];

  const int start = offs[n], end = offs[n+1];
  int e = start;
  for (; e+4 <= end; e += 4){
    int s4[4]; float a0[4], a1[4], x0[4], x1[4];
    #pragma unroll
    for (int j=0;j<4;j++) s4[j] = csrsrc[e+j];
    #pragma unroll
    for (int j=0;j<4;j++){
      a0[j] = als[s4[j]*8 + h0];
      a1[j] = als[s4[j]*8 + h0 + 4];
      x0[j] = xw[(size_t)s4[j]*128 + lane];
      x1[j] = xw[(size_t)s4[j]*128 + 64 + lane];
    }
    #pragma unroll
    for (int j=0;j<4;j++){
      float u0 = a0[j] + ad0; u0 = u0 > 0.f ? u0 : 0.2f*u0;
      float q0 = __expf(u0);
      s0 += q0; acc0 = fmaf(q0, x0[j], acc0);
      float u1 = a1[j] + ad1; u1 = u1 > 0.f ? u1 : 0.2f*u1;
      float q1 = __expf(u1);
      s1 += q1; acc1 = fmaf(q1, x1[j], acc1);
    }
  }
  if (e+2 <= end){
    int sA = csrsrc[e], sB = csrsrc[e+1];
    float aA0 = als[sA*8+h0], aA1 = als[sA*8+h0+4];
    float aB0 = als[sB*8+h0], aB1 = als[sB*8+h0+4];
    float xA0 = xw[(size_t)sA*128+lane], xA1 = xw[(size_t)sA*128+64+lane];
    float xB0 = xw[(size_t)sB*128+lane], xB1 = xw[(size_t)sB*128+64+lane];
    float u;
    u = aA0+ad0; u = u>0.f?u:0.2f*u; float qA0 = __expf(u);
    u = aA1+ad1; u = u>0.f?u:0.2f*u; float qA1 = __expf(u);
    u = aB0+ad0; u = u>0.f?u:0.2f*u; float qB0 = __expf(u);
    u = aB1+ad1; u = u>0.f?u:0.2f*u; float qB1 = __expf(u);
    s0 += qA0+qB0; s1 += qA1+qB1;
    acc0 = fmaf(qA0, xA0, fmaf(qB0, xB0, acc0));
    acc1 = fmaf(qA1, xA1, fmaf(qB1, xB1, acc1));
    e += 2;
  }
  if (e < end){
    int sA = csrsrc[e];
    float aA0 = als[sA*8+h0], aA1 = als[sA*8+h0+4];
    float xA0 = xw[(size_t)sA*128+lane], xA1 = xw[(size_t)sA*128+64+lane];
    float u;
    u = aA0+ad0; u = u>0.f?u:0.2f*u; float qA0 = __expf(u);
    u = aA1+ad1; u = u>0.f?u:0.2f*u; float qA1 = __expf(u);
    s0 += qA0; s1 += qA1;
    acc0 = fmaf(qA0, xA0, acc0);
    acc1 = fmaf(qA1, xA1, acc1);
  }

  float val0 = acc0/s0 + bg[lane];
  float val1 = acc1/s1 + bg[64+lane];
  // LayerNorm across 128 channels = butterfly over this wave (2 ch/lane)
  float sum = val0+val1, sq = val0*val0 + val1*val1;
  #pragma unroll
  for (int off=32; off>=1; off>>=1){ sum += __shfl_xor(sum,off); sq += __shfl_xor(sq,off); }
  float mean = sum*(1.f/128.f);
  float var  = sq*(1.f/128.f) - mean*mean;
  float rr = rsqrtf(var + 1e-5f);
  float y0 = (val0-mean)*rr*lnw[lane]    + lnb[lane];
  float y1 = (val1-mean)*rr*lnw[64+lane] + lnb[64+lane];
  h[(size_t)n*128+lane]    += fmaxf(y0, 0.f);
  h[(size_t)n*128+64+lane] += fmaxf(y1, 0.f);
}

// ---------------- final projection: out = o2@w3 + b3 ----------------
__global__ __launch_bounds__(256) void out_proj(const float* __restrict__ o2,
    const float* __restrict__ w3, const float* __restrict__ b3, float* __restrict__ out)
{
  __shared__ float wsh[256];
  const int tid = threadIdx.x;
  wsh[tid] = w3[tid];
  __syncthreads();
  const int g = blockIdx.x*64 + (tid>>2);
  if (g >= NN) return;
  const int oc = tid&3;
  float s = b3[oc];
  const float* row = &o2[(size_t)g*64];
  #pragma unroll 8
  for (int k=0;k<64;k++) s += row[k]*wsh[k*4+oc];
  out[(size_t)g*4+oc] = s;
}

extern "C" void kernel_launch(void* const* d_in, const int* in_sizes, int n_in,
                              void* d_out, int out_size, void* d_ws, size_t ws_size,
                              hipStream_t stream)
{
  const float* x       = (const float*)d_in[0];
  const int*   ei      = (const int*)d_in[1];
  const float* w_in    = (const float*)d_in[2];
  const float* b_in    = (const float*)d_in[3];
  const float* ln_in_w = (const float*)d_in[4];
  const float* ln_in_b = (const float*)d_in[5];
  const float* Wg      = (const float*)d_in[6];
  const float* a_src   = (const float*)d_in[7];
  const float* a_dst   = (const float*)d_in[8];
  const float* bg      = (const float*)d_in[9];
  const float* lnw     = (const float*)d_in[10];
  const float* lnb     = (const float*)d_in[11];
  const float* w1      = (const float*)d_in[12];
  const float* b1      = (const float*)d_in[13];
  const float* lnow    = (const float*)d_in[14];
  const float* lnob    = (const float*)d_in[15];
  const float* w2      = (const float*)d_in[16];
  const float* b2      = (const float*)d_in[17];
  const float* w3      = (const float*)d_in[18];
  const float* b3      = (const float*)d_in[19];
  float* out = (float*)d_out;

  char* p = (char*)d_ws;
  auto carve = [&](size_t bytes)->void*{
    void* r = (void*)p; p += (bytes + 255) & ~(size_t)255; return r;
  };
  float* h    = (float*)carve((size_t)NN*128*4);
  float* xw   = (float*)carve((size_t)NN*128*4);
  float* als  = (float*)carve((size_t)NN*8*4);
  float* ald  = (float*)carve((size_t)NN*8*4);
  int* offs   = (int*)carve((size_t)(NN+1)*4);
  int* cursor = (int*)carve((size_t)NN*4);
  int* cnt    = (int*)carve((size_t)NN*4);
  int* csrsrc = (int*)carve((size_t)NE*4);
  int* bsum   = (int*)carve(64*4);
  float* o2   = h;

  const int* esrc = ei;
  const int* edst = ei + NE;

  hipMemsetAsync(cnt, 0, (size_t)NN*4, stream);
  count_edges<<<(NE+255)/256, 256, 0, stream>>>(edst, cnt);
  scan1<<<49, 256, 0, stream>>>(cnt, offs, bsum);
  scan2<<<1, 64, 0, stream>>>(bsum);
  scan3<<<(NN+255)/256, 256, 0, stream>>>(offs, bsum, cursor);
  fill_csr<<<(NE+255)/256, 256, 0, stream>>>(esrc, edst, cursor, csrsrc);

  input_mlp<<<NN/2, 256, 0, stream>>>(x, w_in, b_in, ln_in_w, ln_in_b, h);

  for (int i=0;i<4;i++){
    gemm128<128,false,false,false,true><<<NN/32, 256, 0, stream>>>(
        h, Wg + (size_t)i*128*128, nullptr, nullptr, nullptr,
        a_src + i*128, a_dst + i*128, xw, als, ald);
    gat_aggregate<<<NN/4, 256, 0, stream>>>(xw, als, ald, offs, csrsrc,
        bg + i*128, lnw + i*128, lnb + i*128, h);
  }

  gemm128<128,true,true,true,false><<<NN/32, 256, 0, stream>>>(
      h, w1, b1, lnow, lnob, nullptr, nullptr, xw, nullptr, nullptr);
  gemm128<64,true,false,true,false><<<NN/32, 256, 0, stream>>>(
      xw, w2, b2, nullptr, nullptr, nullptr, nullptr, o2, nullptr, nullptr);
  out_proj<<<(NN+63)/64, 256, 0, stream>>>(o2, w3, b3, out);
}

// Round 10
// 656.435 us; speedup vs baseline: 1.2873x; 1.1882x over previous
//
#include <hip/hip_runtime.h>
#include <hip/hip_bf16.h>

#define NN 100000
#define NE 600000

typedef __bf16 bf16x8 __attribute__((ext_vector_type(8)));
typedef float  f32x4  __attribute__((ext_vector_type(4)));

__device__ __forceinline__ float dot4(float4 a, float4 b){
  return a.x*b.x + a.y*b.y + a.z*b.z + a.w*b.w;
}

// ---------------- CSR build (dst-grouped) ----------------
__global__ void count_edges(const int* __restrict__ dst, int* __restrict__ cnt){
  int e = blockIdx.x*256 + threadIdx.x;
  if (e < NE){
    unsigned d = (unsigned)dst[e];
    if (d < NN) atomicAdd(&cnt[d], 1);
  }
}

__global__ void scan1(const int* __restrict__ cnt, int* __restrict__ offs, int* __restrict__ bsum){
  __shared__ int sh[256];
  const int tid = threadIdx.x;
  const int base = blockIdx.x*2048 + tid*8;
  int pre[8]; int s = 0;
  #pragma unroll
  for (int j=0;j<8;j++){
    int idx = base + j;
    int v = (idx < NN) ? cnt[idx] : 0;
    pre[j] = s; s += v;
  }
  sh[tid] = s;
  __syncthreads();
  for (int d=1; d<256; d<<=1){
    int t = (tid >= d) ? sh[tid-d] : 0;
    __syncthreads();
    sh[tid] += t;
    __syncthreads();
  }
  int off = (tid > 0) ? sh[tid-1] : 0;
  #pragma unroll
  for (int j=0;j<8;j++){
    int idx = base + j;
    if (idx < NN) offs[idx] = off + pre[j];
  }
  if (tid == 255) bsum[blockIdx.x] = sh[255];
}

__global__ void scan2(int* __restrict__ bsum){
  if (threadIdx.x == 0){
    int s = 0;
    for (int i=0;i<49;i++){ int t = bsum[i]; bsum[i] = s; s += t; }
  }
}

__global__ void scan3(int* __restrict__ offs, const int* __restrict__ bsum, int* __restrict__ cursor){
  int i = blockIdx.x*256 + threadIdx.x;
  if (i < NN){
    int v = offs[i] + bsum[i>>11];
    offs[i] = v; cursor[i] = v;
  }
  if (i == 0) offs[NN] = NE;
}

__global__ void fill_csr(const int* __restrict__ src, const int* __restrict__ dst,
                         int* __restrict__ cursor, int* __restrict__ csrsrc){
  int e = blockIdx.x*256 + threadIdx.x;
  if (e < NE){
    unsigned d = (unsigned)dst[e];
    unsigned s = (unsigned)src[e];
    if (d < NN && s < NN){
      int p = atomicAdd(&cursor[d], 1);
      csrsrc[p] = (int)s;
    }
  }
}

// ---------------- weight repack: fp32 W[K][C] -> bf16 hi/lo MFMA fragments ----
// Packed layout per matrix: frag index f = (ct*4+ks)*64 + lane, elements f*8+j.
// Element (f,j) = W[ ks*32 + (lane>>4)*8 + j ][ ct*16 + (lane&15) ].
// Offsets in packed buffer (elements): Wg layer i at i*16384, w1 at 65536, w2 at 81920.
__global__ void repack_w(const float* __restrict__ Wg, const float* __restrict__ w1,
                         const float* __restrict__ w2,
                         __bf16* __restrict__ phi, __bf16* __restrict__ plo)
{
  int gid = blockIdx.x*256 + threadIdx.x;
  const float* W; int C; size_t obase; int rem;
  if (gid < 8192)      { W = Wg + (size_t)(gid/2048)*16384; C = 128; obase = (size_t)(gid/2048)*16384; rem = gid % 2048; }
  else if (gid < 10240){ W = w1; C = 128; obase = 65536; rem = gid - 8192; }
  else if (gid < 11264){ W = w2; C = 64;  obase = 81920; rem = gid - 10240; }
  else return;
  const int lane = rem & 63;
  const int tks  = rem >> 6;
  const int ks = tks & 3, t = tks >> 2;
  const int col = t*16 + (lane & 15);
  const int kb  = ks*32 + (lane >> 4)*8;
  const size_t o = obase + (size_t)rem*8;
  #pragma unroll
  for (int j=0;j<8;j++){
    float v = W[(size_t)(kb+j)*C + col];
    __bf16 hb = (__bf16)v;
    phi[o+j] = hb;
    plo[o+j] = (__bf16)(v - (float)hb);
  }
}

// ---------------- input MLP: h = relu(LN(x@w_in+b_in)) ----------------
__global__ __launch_bounds__(256) void input_mlp(const float* __restrict__ x,
    const float* __restrict__ win, const float* __restrict__ b,
    const float* __restrict__ lnw, const float* __restrict__ lnb,
    float* __restrict__ h)
{
  __shared__ float wsh[6*128];
  __shared__ float p2[4][2];
  const int tid = threadIdx.x;
  for (int i=tid;i<768;i+=256) wsh[i] = win[i];
  __syncthreads();
  const int nl = tid>>7, c = tid&127;
  const int n = blockIdx.x*2 + nl;
  float s = b[c];
  #pragma unroll
  for (int k=0;k<6;k++) s += x[n*6+k]*wsh[k*128+c];
  float sum = s, sq = s*s;
  #pragma unroll
  for (int o=32;o>=1;o>>=1){ sum += __shfl_xor(sum,o); sq += __shfl_xor(sq,o); }
  const int wv = tid>>6;
  if ((tid&63)==0){ p2[wv][0]=sum; p2[wv][1]=sq; }
  __syncthreads();
  float ts = p2[nl*2][0]+p2[nl*2+1][0];
  float tq = p2[nl*2][1]+p2[nl*2+1][1];
  float mean = ts*(1.f/128.f);
  float var  = tq*(1.f/128.f) - mean*mean;
  float y = (s-mean)*rsqrtf(var+1e-5f)*lnw[c]+lnb[c];
  h[(size_t)n*128+c] = fmaxf(y, 0.f);
}

// ---------------- MFMA split-bf16 GEMM: Y = act(LN?(X@W + b)), K=128 ----------
// 4 waves/block, 16 rows/wave, C cols. A-frags from global fp32 (hi/lo split);
// B-frags from the repacked buffers (coalesced bf16x8). 3 MFMAs per k-step
// (hi*hi + lo*hi + hi*lo) -> fp32-grade accuracy on the 2.5 PF matrix pipe.
// Layouts: A m=lane&15, k=ks*32+(lane>>4)*8+j; B n=lane&15, same k;
// C/D col=lane&15, row=(lane>>4)*4+i (HW-verified mapping).
template<int C, bool HAS_BIAS, bool DO_LN, bool DO_RELU, bool GAT>
__global__ __launch_bounds__(256) void gemm_mfma(const float* __restrict__ X,
    const __bf16* __restrict__ Bhi, const __bf16* __restrict__ Blo,
    const float* __restrict__ bias,
    const float* __restrict__ lnw, const float* __restrict__ lnb,
    const float* __restrict__ asrc, const float* __restrict__ adst,
    float* __restrict__ Y, float* __restrict__ als, float* __restrict__ ald)
{
  constexpr int NT = C/16;
  const int tid = threadIdx.x;
  const int wid = tid >> 6, lane = tid & 63;
  const int lrow = lane & 15, lgrp = lane >> 4;
  const int m0 = (blockIdx.x*4 + wid)*16;

  // A fragments: 4 k-steps, hi/lo
  bf16x8 Ahi[4], Alo[4];
  {
    int row = m0 + lrow; if (row >= NN) row = NN-1;
    const float* Xr = X + (size_t)row*128 + lgrp*8;
    #pragma unroll
    for (int ks=0; ks<4; ks++){
      float4 u0 = *(const float4*)(Xr + ks*32);
      float4 u1 = *(const float4*)(Xr + ks*32 + 4);
      float v[8] = {u0.x,u0.y,u0.z,u0.w,u1.x,u1.y,u1.z,u1.w};
      bf16x8 h8, l8;
      #pragma unroll
      for (int j=0;j<8;j++){
        __bf16 hb = (__bf16)v[j];
        h8[j] = hb;
        l8[j] = (__bf16)(v[j] - (float)hb);
      }
      Ahi[ks] = h8; Alo[ks] = l8;
    }
  }

  f32x4 acc[NT];
  #pragma unroll
  for (int t=0;t<NT;t++){ acc[t] = (f32x4){0.f,0.f,0.f,0.f}; }

  const bf16x8* B8h = (const bf16x8*)Bhi;
  const bf16x8* B8l = (const bf16x8*)Blo;
  #pragma unroll
  for (int t=0;t<NT;t++){
    #pragma unroll
    for (int ks=0;ks<4;ks++){
      bf16x8 bh = B8h[(t*4+ks)*64 + lane];
      bf16x8 bl = B8l[(t*4+ks)*64 + lane];
      acc[t] = __builtin_amdgcn_mfma_f32_16x16x32_bf16(Ahi[ks], bh, acc[t], 0,0,0);
      acc[t] = __builtin_amdgcn_mfma_f32_16x16x32_bf16(Alo[ks], bh, acc[t], 0,0,0);
      acc[t] = __builtin_amdgcn_mfma_f32_16x16x32_bf16(Ahi[ks], bl, acc[t], 0,0,0);
    }
  }

  if constexpr (HAS_BIAS){
    #pragma unroll
    for (int t=0;t<NT;t++){
      float bv = bias[t*16 + lrow];
      #pragma unroll
      for (int i=0;i<4;i++) acc[t][i] += bv;
    }
  }

  if constexpr (GAT){
    // Y store + per-head attention logits (head h == column tile t)
    #pragma unroll
    for (int t=0;t<NT;t++){
      float av = asrc[t*16 + lrow];
      float dv2 = adst[t*16 + lrow];
      float ps[4], pd[4];
      #pragma unroll
      for (int i=0;i<4;i++){
        int n = m0 + lgrp*4 + i;
        if (n < NN) Y[(size_t)n*C + t*16 + lrow] = acc[t][i];
        ps[i] = acc[t][i]*av; pd[i] = acc[t][i]*dv2;
      }
      #pragma unroll
      for (int off=1; off<16; off<<=1){
        #pragma unroll
        for (int i=0;i<4;i++){
          ps[i] += __shfl_xor(ps[i], off);
          pd[i] += __shfl_xor(pd[i], off);
        }
      }
      if (lrow == 0){
        #pragma unroll
        for (int i=0;i<4;i++){
          int n = m0 + lgrp*4 + i;
          if (n < NN){ als[n*8 + t] = ps[i]; ald[n*8 + t] = pd[i]; }
        }
      }
    }
  } else {
    if constexpr (DO_LN){
      float s[4] = {0,0,0,0}, q[4] = {0,0,0,0};
      #pragma unroll
      for (int t=0;t<NT;t++){
        #pragma unroll
        for (int i=0;i<4;i++){ s[i] += acc[t][i]; q[i] += acc[t][i]*acc[t][i]; }
      }
      #pragma unroll
      for (int off=1; off<16; off<<=1){
        #pragma unroll
        for (int i=0;i<4;i++){ s[i] += __shfl_xor(s[i], off); q[i] += __shfl_xor(q[i], off); }
      }
      float mean[4], rr[4];
      #pragma unroll
      for (int i=0;i<4;i++){
        mean[i] = s[i]*(1.0f/C);
        float var = q[i]*(1.0f/C) - mean[i]*mean[i];
        rr[i] = rsqrtf(var + 1e-5f);
      }
      #pragma unroll
      for (int t=0;t<NT;t++){
        float lw = lnw[t*16 + lrow], lb = lnb[t*16 + lrow];
        #pragma unroll
        for (int i=0;i<4;i++){
          float v = (acc[t][i]-mean[i])*rr[i]*lw + lb;
          if constexpr (DO_RELU) v = fmaxf(v, 0.f);
          acc[t][i] = v;
        }
      }
    } else if constexpr (DO_RELU){
      #pragma unroll
      for (int t=0;t<NT;t++){
        #pragma unroll
        for (int i=0;i<4;i++) acc[t][i] = fmaxf(acc[t][i], 0.f);
      }
    }
    #pragma unroll
    for (int t=0;t<NT;t++){
      #pragma unroll
      for (int i=0;i<4;i++){
        int n = m0 + lgrp*4 + i;
        if (n < NN) Y[(size_t)n*C + t*16 + lrow] = acc[t][i];
      }
    }
  }
}

// ---------------- per-node softmax + aggregate + LN + residual ----------------
// One wave per node, lane = channel pair (c, c+64). No max-subtraction:
// logits are O(1) (0.05-scale weights), so exp() is safe in fp32 and softmax
// is shift-invariant. Private per-lane accumulation, no LDS, no barriers.
__global__ __launch_bounds__(256) void gat_aggregate(
    const float* __restrict__ xw, const float* __restrict__ als, const float* __restrict__ ald,
    const int* __restrict__ offs, const int* __restrict__ csrsrc,
    const float* __restrict__ bg, const float* __restrict__ lnw, const float* __restrict__ lnb,
    float* __restrict__ h)
{
  const int wv = threadIdx.x >> 6, lane = threadIdx.x & 63;
  const int n = blockIdx.x*4 + wv;
  const int h0 = lane >> 4;                 // head of channel c=lane; c+64 -> h0+4
  const float ad0 = ald[n*8 + h0];
  const float ad1 = ald[n*8 + h0 + 4];

  // self-loop
  float t0 = als[n*8 + h0] + ad0;     t0 = t0 > 0.f ? t0 : 0.2f*t0;
  float t1 = als[n*8 + h0 + 4] + ad1; t1 = t1 > 0.f ? t1 : 0.2f*t1;
  float p0 = __expf(t0), p1 = __expf(t1);
  float s0 = p0, s1 = p1;
  float acc0 = p0 * xw[(size_t)n*128 + lane];
  float acc1 = p1 * xw[(size_t)n*128 + 64 + lane];

  const int start = offs[n], end = offs[n+1];
  int e = start;
  for (; e+4 <= end; e += 4){
    int s4[4]; float a0[4], a1[4], x0[4], x1[4];
    #pragma unroll
    for (int j=0;j<4;j++) s4[j] = csrsrc[e+j];
    #pragma unroll
    for (int j=0;j<4;j++){
      a0[j] = als[s4[j]*8 + h0];
      a1[j] = als[s4[j]*8 + h0 + 4];
      x0[j] = xw[(size_t)s4[j]*128 + lane];
      x1[j] = xw[(size_t)s4[j]*128 + 64 + lane];
    }
    #pragma unroll
    for (int j=0;j<4;j++){
      float u0 = a0[j] + ad0; u0 = u0 > 0.f ? u0 : 0.2f*u0;
      float q0 = __expf(u0);
      s0 += q0; acc0 = fmaf(q0, x0[j], acc0);
      float u1 = a1[j] + ad1; u1 = u1 > 0.f ? u1 : 0.2f*u1;
      float q1 = __expf(u1);
      s1 += q1; acc1 = fmaf(q1, x1[j], acc1);
    }
  }
  if (e+2 <= end){
    int sA = csrsrc[e], sB = csrsrc[e+1];
    float aA0 = als[sA*8+h0], aA1 = als[sA*8+h0+4];
    float aB0 = als[sB*8+h0], aB1 = als[sB*8+h0+4];
    float xA0 = xw[(size_t)sA*128+lane], xA1 = xw[(size_t)sA*128+64+lane];
    float xB0 = xw[(size_t)sB*128+lane], xB1 = xw[(size_t)sB*128+64+lane];
    float u;
    u = aA0+ad0; u = u>0.f?u:0.2f*u; float qA0 = __expf(u);
    u = aA1+ad1; u = u>0.f?u:0.2f*u; float qA1 = __expf(u);
    u = aB0+ad0; u = u>0.f?u:0.2f*u; float qB0 = __expf(u);
    u = aB1+ad1; u = u>0.f?u:0.2f*u; float qB1 = __expf(u);
    s0 += qA0+qB0; s1 += qA1+qB1;
    acc0 = fmaf(qA0, xA0, fmaf(qB0, xB0, acc0));
    acc1 = fmaf(qA1, xA1, fmaf(qB1, xB1, acc1));
    e += 2;
  }
  if (e < end){
    int sA = csrsrc[e];
    float aA0 = als[sA*8+h0], aA1 = als[sA*8+h0+4];
    float xA0 = xw[(size_t)sA*128+lane], xA1 = xw[(size_t)sA*128+64+lane];
    float u;
    u = aA0+ad0; u = u>0.f?u:0.2f*u; float qA0 = __expf(u);
    u = aA1+ad1; u = u>0.f?u:0.2f*u; float qA1 = __expf(u);
    s0 += qA0; s1 += qA1;
    acc0 = fmaf(qA0, xA0, acc0);
    acc1 = fmaf(qA1, xA1, acc1);
  }

  float val0 = acc0/s0 + bg[lane];
  float val1 = acc1/s1 + bg[64+lane];
  // LayerNorm across 128 channels = butterfly over this wave (2 ch/lane)
  float sum = val0+val1, sq = val0*val0 + val1*val1;
  #pragma unroll
  for (int off=32; off>=1; off>>=1){ sum += __shfl_xor(sum,off); sq += __shfl_xor(sq,off); }
  float mean = sum*(1.f/128.f);
  float var  = sq*(1.f/128.f) - mean*mean;
  float rr = rsqrtf(var + 1e-5f);
  float y0 = (val0-mean)*rr*lnw[lane]    + lnb[lane];
  float y1 = (val1-mean)*rr*lnw[64+lane] + lnb[64+lane];
  h[(size_t)n*128+lane]    += fmaxf(y0, 0.f);
  h[(size_t)n*128+64+lane] += fmaxf(y1, 0.f);
}

// ---------------- final projection: out = o2@w3 + b3 ----------------
__global__ __launch_bounds__(256) void out_proj(const float* __restrict__ o2,
    const float* __restrict__ w3, const float* __restrict__ b3, float* __restrict__ out)
{
  __shared__ float wsh[256];
  const int tid = threadIdx.x;
  wsh[tid] = w3[tid];
  __syncthreads();
  const int g = blockIdx.x*64 + (tid>>2);
  if (g >= NN) return;
  const int oc = tid&3;
  float s = b3[oc];
  const float* row = &o2[(size_t)g*64];
  #pragma unroll 8
  for (int k=0;k<64;k++) s += row[k]*wsh[k*4+oc];
  out[(size_t)g*4+oc] = s;
}

extern "C" void kernel_launch(void* const* d_in, const int* in_sizes, int n_in,
                              void* d_out, int out_size, void* d_ws, size_t ws_size,
                              hipStream_t stream)
{
  const float* x       = (const float*)d_in[0];
  const int*   ei      = (const int*)d_in[1];
  const float* w_in    = (const float*)d_in[2];
  const float* b_in    = (const float*)d_in[3];
  const float* ln_in_w = (const float*)d_in[4];
  const float* ln_in_b = (const float*)d_in[5];
  const float* Wg      = (const float*)d_in[6];
  const float* a_src   = (const float*)d_in[7];
  const float* a_dst   = (const float*)d_in[8];
  const float* bg      = (const float*)d_in[9];
  const float* lnw     = (const float*)d_in[10];
  const float* lnb     = (const float*)d_in[11];
  const float* w1      = (const float*)d_in[12];
  const float* b1      = (const float*)d_in[13];
  const float* lnow    = (const float*)d_in[14];
  const float* lnob    = (const float*)d_in[15];
  const float* w2      = (const float*)d_in[16];
  const float* b2      = (const float*)d_in[17];
  const float* w3      = (const float*)d_in[18];
  const float* b3      = (const float*)d_in[19];
  float* out = (float*)d_out;

  char* p = (char*)d_ws;
  auto carve = [&](size_t bytes)->void*{
    void* r = (void*)p; p += (bytes + 255) & ~(size_t)255; return r;
  };
  float* h    = (float*)carve((size_t)NN*128*4);
  float* xw   = (float*)carve((size_t)NN*128*4);
  float* als  = (float*)carve((size_t)NN*8*4);
  float* ald  = (float*)carve((size_t)NN*8*4);
  int* offs   = (int*)carve((size_t)(NN+1)*4);
  int* cursor = (int*)carve((size_t)NN*4);
  int* cnt    = (int*)carve((size_t)NN*4);
  int* csrsrc = (int*)carve((size_t)NE*4);
  int* bsum   = (int*)carve(64*4);
  __bf16* pWhi = (__bf16*)carve((size_t)90112*2);
  __bf16* pWlo = (__bf16*)carve((size_t)90112*2);
  float* o2   = h;

  const int* esrc = ei;
  const int* edst = ei + NE;

  // one-time weight repack into MFMA fragment layout (bf16 hi/lo)
  repack_w<<<44, 256, 0, stream>>>(Wg, w1, w2, pWhi, pWlo);

  hipMemsetAsync(cnt, 0, (size_t)NN*4, stream);
  count_edges<<<(NE+255)/256, 256, 0, stream>>>(edst, cnt);
  scan1<<<49, 256, 0, stream>>>(cnt, offs, bsum);
  scan2<<<1, 64, 0, stream>>>(bsum);
  scan3<<<(NN+255)/256, 256, 0, stream>>>(offs, bsum, cursor);
  fill_csr<<<(NE+255)/256, 256, 0, stream>>>(esrc, edst, cursor, csrsrc);

  input_mlp<<<NN/2, 256, 0, stream>>>(x, w_in, b_in, ln_in_w, ln_in_b, h);

  const int GRID = (NN + 63) / 64;   // 1563
  for (int i=0;i<4;i++){
    gemm_mfma<128,false,false,false,true><<<GRID, 256, 0, stream>>>(
        h, pWhi + (size_t)i*16384, pWlo + (size_t)i*16384, nullptr, nullptr, nullptr,
        a_src + i*128, a_dst + i*128, xw, als, ald);
    gat_aggregate<<<NN/4, 256, 0, stream>>>(xw, als, ald, offs, csrsrc,
        bg + i*128, lnw + i*128, lnb + i*128, h);
  }

  gemm_mfma<128,true,true,true,false><<<GRID, 256, 0, stream>>>(
      h, pWhi + 65536, pWlo + 65536, b1, lnow, lnob, nullptr, nullptr, xw, nullptr, nullptr);
  gemm_mfma<64,true,false,true,false><<<GRID, 256, 0, stream>>>(
      xw, pWhi + 81920, pWlo + 81920, b2, nullptr, nullptr, nullptr, nullptr, o2, nullptr, nullptr);
  out_proj<<<(NN+63)/64, 256, 0, stream>>>(o2, w3, b3, out);
}